// Round 4
// baseline (761.536 us; speedup 1.0000x reference)
//
#include <hip/hip_runtime.h>
#include <hip/hip_bf16.h>

// BinTreeNetwork (ALL TENSORS FP32):
//   out[B, o] = out0[o] + out_bias[o]
//             + sum_{i=0}^{20} res_i[B mod 2^{i+1}, :] . out_layers[i][o, :]
// res tables (2^{i+1} rows x 2 cols, fp32) for levels 0..16 in ws;
// levels 17..20 computed on the fly in k_final via two register chains
// from the two level-16 ancestor rows (b<<16)|(B&0xFFFF).
//   res_j[m,k'] = sum_k res_{j-1}[src,k] * W_s(layer j-1)[k',k] + b_s[k']
//   src = ((m>>j)<<(j-1)) | (m & (2^{j-1}-1)),  s = (m>>(j-1))&1  (drop 2nd-MSB)
//
// ws layout (fp32 elements):
//   [0, 2^19-4)  res tables, level i at (1<<(i+2))-4
//   P0 = 1<<19:
//     +0      base[32]     = out0.x + out_bias
//     +32     outLf[21*64] = out_layers copy
//     +1376   tLf[84], +1460 tRf[84], +1544 tLbf[42], +1586 tRbf[42]
//     +2048   C7[256*32]   = base + levels 0..7 pre-folded
// total ws: (2^19 + 10240)*4 B ~= 2.14 MB

#define P0 (1u << 19)

typedef float floatx4 __attribute__((ext_vector_type(4)));

// ---------------- K1: seed + levels 1..13 + param copy + C7 (1 block) --------
__global__ __launch_bounds__(1024) void k_prefix(
    const float* __restrict__ x,
    const float* __restrict__ inL,
    const float* __restrict__ inR,
    const float* __restrict__ inLb,
    const float* __restrict__ inRb,
    const float* __restrict__ treeL,
    const float* __restrict__ treeR,
    const float* __restrict__ treeLb,
    const float* __restrict__ treeRb,
    const float* __restrict__ outL0,
    const float* __restrict__ outLs,
    const float* __restrict__ outB,
    float* __restrict__ ws)
{
    __shared__ float xs[4096];
    __shared__ float dots[36];
    const int tid = threadIdx.x;

    for (int i = tid; i < 4096; i += 1024) xs[i] = x[i];
    __syncthreads();

    const int wave = tid >> 6, lane = tid & 63;
    for (int d = wave; d < 36; d += 16) {
        const float* row =
            (d < 2) ? inL + d * 4096 :
            (d < 4) ? inR + (d - 2) * 4096 :
                      outL0 + (d - 4) * 4096;
        float s = 0.f;
        for (int k = lane; k < 4096; k += 64) s += row[k] * xs[k];
        #pragma unroll
        for (int off = 32; off; off >>= 1) s += __shfl_down(s, off, 64);
        if (lane == 0) dots[d] = s;
    }
    __syncthreads();

    float* base  = ws + P0;
    float* outLf = ws + P0 + 32;
    float* tLf   = ws + P0 + 1376;
    float* tRf   = ws + P0 + 1460;
    float* tLbf  = ws + P0 + 1544;
    float* tRbf  = ws + P0 + 1586;
    float* C7    = ws + P0 + 2048;

    for (int i = tid; i < 21 * 64; i += 1024) outLf[i] = outLs[i];
    if (tid < 84)                      tLf[tid]        = treeL[tid];
    else if (tid < 168)                tRf[tid - 84]   = treeR[tid - 84];
    else if (tid < 210)                tLbf[tid - 168] = treeLb[tid - 168];
    else if (tid < 252)                tRbf[tid - 210] = treeRb[tid - 210];
    if (tid < 32) base[tid] = dots[4 + tid] + outB[tid];
    if (tid < 2) {
        // res_0 row j = {left0[j], right0[j]}
        ws[tid * 2 + 0] = dots[tid]     + inLb[tid];
        ws[tid * 2 + 1] = dots[2 + tid] + inRb[tid];
    }
    __syncthreads();

    // levels 1..13
    for (int i = 1; i <= 13; ++i) {
        const float* prev = ws + ((1u << (i + 1)) - 4);
        float* cur        = ws + ((1u << (i + 2)) - 4);
        const int rows = 1 << (i + 1);
        const int lowmask = (1 << (i - 1)) - 1;
        for (int m = tid; m < rows; m += 1024) {
            const int src = ((m >> i) << (i - 1)) | (m & lowmask);
            const int s = (m >> (i - 1)) & 1;
            const float* W  = (s ? tRf  : tLf)  + (i - 1) * 4;
            const float* bb = (s ? tRbf : tLbf) + (i - 1) * 2;
            const float p0 = prev[src * 2], p1 = prev[src * 2 + 1];
            cur[m * 2 + 0] = W[0] * p0 + W[1] * p1 + bb[0];
            cur[m * 2 + 1] = W[2] * p0 + W[3] * p1 + bb[1];
        }
        __syncthreads();
    }

    // C7[m][o] = base[o] + sum_{i=0}^{7} res_i[m mod 2^{i+1}] . outL[i][o]
    for (int idx = tid; idx < 8192; idx += 1024) {
        const int m = idx >> 5, o = idx & 31;
        float s = base[o];
        #pragma unroll
        for (int i = 0; i < 8; ++i) {
            const float* ri = ws + ((1u << (i + 2)) - 4) + (m & ((2 << i) - 1)) * 2;
            s += ri[0] * outLf[i * 64 + o * 2] + ri[1] * outLf[i * 64 + o * 2 + 1];
        }
        C7[idx] = s;
    }
}

// ---------------- K2: levels 14..16 via per-block register chains from res_13 -
__global__ __launch_bounds__(256) void k_mid(float* __restrict__ ws)
{
    const int blk = blockIdx.x;
    int j, b;
    if      (blk < 16) { j = 14; b = blk; }
    else if (blk < 48) { j = 15; b = blk - 16; }
    else               { j = 16; b = blk - 48; }

    const float* tLf  = ws + P0 + 1376;
    const float* tRf  = ws + P0 + 1460;
    const float* tLbf = ws + P0 + 1544;
    const float* tRbf = ws + P0 + 1586;

    // walk base row from level j down to 13, recording per-level select bits
    unsigned m = (unsigned)b << 11;
    const unsigned basej = m;
    unsigned sbits = 0;
    for (int l = j; l > 13; --l) {
        sbits |= ((m >> (l - 1)) & 1u) << l;
        m = ((m >> l) << (l - 1)) | (m & ((1u << (l - 1)) - 1));
    }

    // this thread's 8 rows of res_13 (aligned float4 x4)
    const int r0 = threadIdx.x * 8;
    const floatx4* s4 = (const floatx4*)(ws + ((1u << 15) - 4) + (m + r0) * 2);
    floatx4 a0 = s4[0], a1 = s4[1], a2 = s4[2], a3 = s4[3];
    float r[8][2] = {{a0.x,a0.y},{a0.z,a0.w},{a1.x,a1.y},{a1.z,a1.w},
                     {a2.x,a2.y},{a2.z,a2.w},{a3.x,a3.y},{a3.z,a3.w}};

    for (int l = 14; l <= j; ++l) {
        const int s = (sbits >> l) & 1;
        const float* W  = (s ? tRf  : tLf)  + (l - 1) * 4;
        const float* bb = (s ? tRbf : tLbf) + (l - 1) * 2;
        const float w00 = W[0], w01 = W[1], w10 = W[2], w11 = W[3];
        const float b0 = bb[0], b1 = bb[1];
        #pragma unroll
        for (int q = 0; q < 8; ++q) {
            const float p0 = r[q][0], p1 = r[q][1];
            r[q][0] = w00 * p0 + w01 * p1 + b0;
            r[q][1] = w10 * p0 + w11 * p1 + b1;
        }
    }

    floatx4* d4 = (floatx4*)(ws + ((1u << (j + 2)) - 4) + (basej + r0) * 2);
    d4[0] = (floatx4){r[0][0], r[0][1], r[1][0], r[1][1]};
    d4[1] = (floatx4){r[2][0], r[2][1], r[3][0], r[3][1]};
    d4[2] = (floatx4){r[4][0], r[4][1], r[5][0], r[5][1]};
    d4[3] = (floatx4){r[6][0], r[6][1], r[7][0], r[7][1]};
}

// ---------------- K3: final gather-sum, 1 thread per leaf --------------------
__global__ __launch_bounds__(256) void k_final(const float* __restrict__ ws,
                                               float* __restrict__ out)
{
    const unsigned B = blockIdx.x * 256u + threadIdx.x;
    const float* outLf = ws + P0 + 32;
    const float* tLf   = ws + P0 + 1376;
    const float* tRf   = ws + P0 + 1460;
    const float* tLbf  = ws + P0 + 1544;
    const float* tRbf  = ws + P0 + 1586;
    const float* C7    = ws + P0 + 2048;

    float acc[32];
    {   // C7 row (contiguous 128 B, 16B-aligned)
        const floatx4* c4 = (const floatx4*)(C7 + (B & 255u) * 32);
        #pragma unroll
        for (int q = 0; q < 8; ++q) {
            floatx4 v = c4[q];
            acc[q * 4 + 0] = v.x; acc[q * 4 + 1] = v.y;
            acc[q * 4 + 2] = v.z; acc[q * 4 + 3] = v.w;
        }
    }

    // levels 8..15 from tables
    float p[8][2];
    #pragma unroll
    for (int i = 8; i <= 15; ++i) {
        const float2* ri = (const float2*)(ws + ((1u << (i + 2)) - 4)
                                              + (B & ((2u << i) - 1)) * 2);
        float2 v = *ri;
        p[i - 8][0] = v.x;
        p[i - 8][1] = v.y;
    }
    #pragma unroll
    for (int i = 0; i < 8; ++i) {
        const float* cf = outLf + (i + 8) * 64;   // uniform -> scalar loads
        const float q0 = p[i][0], q1 = p[i][1];
        #pragma unroll
        for (int o = 0; o < 32; ++o)
            acc[o] += q0 * cf[o * 2] + q1 * cf[o * 2 + 1];
    }

    // levels 16..20: two register chains from the two level-16 ancestor rows
    // ancestor at level 16 of contribution-level l's row = (B_l<<16)|(B&0xFFFF);
    // shared select bits s_j = B_{j-1}; contribution l picks chain B_l.
    {
        const unsigned Blo = B & 0xFFFFu;
        const float* r16 = ws + ((1u << 18) - 4);
        const float2* rA = (const float2*)(r16 + Blo * 2);
        const float2* rC = (const float2*)(r16 + (Blo + 65536u) * 2);
        float2 vA = *rA, vC = *rC;
        float A0 = vA.x, A1 = vA.y;   // MSB=0 chain
        float c0 = vC.x, c1 = vC.y;   // MSB=1 chain
        {   // level 16 contribution
            const int pick = (B >> 16) & 1;
            const float q0 = pick ? c0 : A0, q1 = pick ? c1 : A1;
            const float* cf = outLf + 16 * 64;
            #pragma unroll
            for (int o = 0; o < 32; ++o)
                acc[o] += q0 * cf[o * 2] + q1 * cf[o * 2 + 1];
        }
        #pragma unroll
        for (int l = 17; l <= 20; ++l) {
            const int s = (B >> (l - 1)) & 1;
            const float* WL = tLf + (l - 1) * 4;   // uniform -> scalar loads
            const float* WR = tRf + (l - 1) * 4;
            const float* bL = tLbf + (l - 1) * 2;
            const float* bR = tRbf + (l - 1) * 2;
            const float w00 = s ? WR[0] : WL[0], w01 = s ? WR[1] : WL[1];
            const float w10 = s ? WR[2] : WL[2], w11 = s ? WR[3] : WL[3];
            const float b0  = s ? bR[0] : bL[0], b1  = s ? bR[1] : bL[1];
            const float nA0 = w00 * A0 + w01 * A1 + b0;
            const float nA1 = w10 * A0 + w11 * A1 + b1;
            const float nc0 = w00 * c0 + w01 * c1 + b0;
            const float nc1 = w10 * c0 + w11 * c1 + b1;
            A0 = nA0; A1 = nA1; c0 = nc0; c1 = nc1;
            const int pick = (B >> l) & 1;
            const float q0 = pick ? c0 : A0, q1 = pick ? c1 : A1;
            const float* cf = outLf + l * 64;
            #pragma unroll
            for (int o = 0; o < 32; ++o)
                acc[o] += q0 * cf[o * 2] + q1 * cf[o * 2 + 1];
        }
    }

    // fp32 output, nontemporal 16B stores (128 B/thread, fully coalesced)
    floatx4* dst = (floatx4*)(out + (size_t)B * 32);
    #pragma unroll
    for (int q = 0; q < 8; ++q) {
        floatx4 v = {acc[q * 4 + 0], acc[q * 4 + 1],
                     acc[q * 4 + 2], acc[q * 4 + 3]};
        __builtin_nontemporal_store(v, dst + q);
    }
}

extern "C" void kernel_launch(void* const* d_in, const int* in_sizes, int n_in,
                              void* d_out, int out_size, void* d_ws, size_t ws_size,
                              hipStream_t stream) {
    const float* x     = (const float*)d_in[0];
    const float* inL   = (const float*)d_in[1];
    const float* inR   = (const float*)d_in[2];
    const float* inLb  = (const float*)d_in[3];
    const float* inRb  = (const float*)d_in[4];
    const float* treeL = (const float*)d_in[5];
    const float* treeR = (const float*)d_in[6];
    const float* treeLb= (const float*)d_in[7];
    const float* treeRb= (const float*)d_in[8];
    const float* outL0 = (const float*)d_in[9];
    const float* outLs = (const float*)d_in[10];
    const float* outB  = (const float*)d_in[11];
    float* ws = (float*)d_ws;
    float* out = (float*)d_out;

    hipLaunchKernelGGL(k_prefix, dim3(1), dim3(1024), 0, stream,
                       x, inL, inR, inLb, inRb, treeL, treeR, treeLb, treeRb,
                       outL0, outLs, outB, ws);
    hipLaunchKernelGGL(k_mid, dim3(112), dim3(256), 0, stream, ws);
    hipLaunchKernelGGL(k_final, dim3(1u << 13), dim3(256), 0, stream, ws, out);
}